// Round 1
// baseline (531.477 us; speedup 1.0000x reference)
//
#include <hip/hip_runtime.h>
#include <cmath>

// Per-element: loss_b = max_c [ hinge(xy_c) ],  xy_c = (M @ d_c).xy / (M @ d_c).z / [W,H]
// where M = Pr_b @ Rv_bᵀ  and  d_c = K⁻¹ @ corner_c  (4 host-computed constants).
// Rv from normalized quaternion, Pr = real_projection_t[b, 6].

__global__ __launch_bounds__(256) void loss_kernel(
    const float* __restrict__ Vt,       // [B,4]
    const float* __restrict__ Prt,      // [B,12,3,3] row-major
    float* __restrict__ out,            // [1], pre-zeroed
    int B,
    float d0x, float d0y, float d1x, float d1y,
    float d2x, float d2y, float d3x, float d3y)
{
    int b = blockIdx.x * blockDim.x + threadIdx.x;
    float loss = 0.0f;
    if (b < B) {
        // ---- quaternion -> rotation matrix (normalized) ----
        float4 q4 = *reinterpret_cast<const float4*>(Vt + 4ll * b);
        float qx = q4.x, qy = q4.y, qz = q4.z, qw = q4.w;
        float n  = sqrtf(qx*qx + qy*qy + qz*qz + qw*qw);
        float in_ = 1.0f / n;
        qx *= in_; qy *= in_; qz *= in_; qw *= in_;
        float r00 = 1.0f - 2.0f*(qy*qy + qz*qz);
        float r01 = 2.0f*(qx*qy - qz*qw);
        float r02 = 2.0f*(qx*qz + qy*qw);
        float r10 = 2.0f*(qx*qy + qz*qw);
        float r11 = 1.0f - 2.0f*(qx*qx + qz*qz);
        float r12 = 2.0f*(qy*qz - qx*qw);
        float r20 = 2.0f*(qx*qz - qy*qw);
        float r21 = 2.0f*(qy*qz + qx*qw);
        float r22 = 1.0f - 2.0f*(qx*qx + qy*qy);

        // ---- Pr = real_projection_t[b, 6] : 9 floats at float-offset b*108+54 (8B aligned) ----
        const float* P = Prt + (size_t)b * 108 + 54;
        float2 a0 = *reinterpret_cast<const float2*>(P + 0);
        float2 a1 = *reinterpret_cast<const float2*>(P + 2);
        float2 a2 = *reinterpret_cast<const float2*>(P + 4);
        float2 a3 = *reinterpret_cast<const float2*>(P + 6);
        float  p8 = P[8];
        float P0=a0.x, P1=a0.y, P2=a1.x, P3=a1.y, P4=a2.x, P5=a2.y, P6=a3.x, P7=a3.y, P8=p8;

        // ---- M = Pr @ Rvᵀ :  M[i][j] = sum_k Pr[i][k] * Rv[j][k] ----
        float m00 = P0*r00 + P1*r01 + P2*r02;
        float m01 = P0*r10 + P1*r11 + P2*r12;
        float m02 = P0*r20 + P1*r21 + P2*r22;
        float m10 = P3*r00 + P4*r01 + P5*r02;
        float m11 = P3*r10 + P4*r11 + P5*r12;
        float m12 = P3*r20 + P4*r21 + P5*r22;
        float m20 = P6*r00 + P7*r01 + P8*r02;
        float m21 = P6*r10 + P7*r11 + P8*r12;
        float m22 = P6*r20 + P7*r21 + P8*r22;

        const float invW = 1.0f / 1920.0f, invH = 1.0f / 1080.0f;
        float best = -1e30f;
        float dxs[4] = {d0x, d1x, d2x, d3x};
        float dys[4] = {d0y, d1y, d2y, d3y};
        #pragma unroll
        for (int c = 0; c < 4; ++c) {
            float dx = dxs[c], dy = dys[c];
            float px = m00*dx + m01*dy + m02;
            float py = m10*dx + m11*dy + m12;
            float pz = m20*dx + m21*dy + m22;
            float rz = 1.0f / pz;                 // accurate divide
            float x  = px * rz * invW;
            float y  = py * rz * invH;
            float v  = fmaxf(0.0f, -x) + fmaxf(0.0f, x - 1.0f)
                     + fmaxf(0.0f, -y) + fmaxf(0.0f, y - 1.0f);
            best = fmaxf(best, v);
        }
        loss = best;
    }

    // ---- block reduction: wave shuffle -> LDS -> one atomic per block ----
    #pragma unroll
    for (int off = 32; off > 0; off >>= 1)
        loss += __shfl_down(loss, off, 64);
    __shared__ float smem[4];
    int lane = threadIdx.x & 63;
    int wv   = threadIdx.x >> 6;
    if (lane == 0) smem[wv] = loss;
    __syncthreads();
    if (threadIdx.x == 0) {
        float s = smem[0] + smem[1] + smem[2] + smem[3];
        atomicAdd(out, s);
    }
}

extern "C" void kernel_launch(void* const* d_in, const int* in_sizes, int n_in,
                              void* d_out, int out_size, void* d_ws, size_t ws_size,
                              hipStream_t stream) {
    const float* Vt  = (const float*)d_in[0];
    const float* Prt = (const float*)d_in[1];
    float* out = (float*)d_out;
    int B = in_sizes[0] / 4;

    // Host-side constants: K⁻¹ @ corner_c
    const double fd = 0.5 * 1080.0 / tan(0.5 * 0.8);
    const float  f  = (float)fd;
    const float  cx = 0.5f * 1920.0f, cy = 0.5f * 1080.0f;
    const float  x0 = 192.0f, x1 = 1728.0f, y0 = 108.0f, y1 = 972.0f;
    // corner order matches reference: (x0,y0),(x0,y1),(x1,y0),(x1,y1)
    float d0x = (x0 - cx) / f, d0y = (y0 - cy) / f;
    float d1x = (x0 - cx) / f, d1y = (y1 - cy) / f;
    float d2x = (x1 - cx) / f, d2y = (y0 - cy) / f;
    float d3x = (x1 - cx) / f, d3y = (y1 - cy) / f;

    hipMemsetAsync(d_out, 0, sizeof(float), stream);
    int threads = 256;
    int blocks  = (B + threads - 1) / threads;
    loss_kernel<<<blocks, threads, 0, stream>>>(Vt, Prt, out, B,
        d0x, d0y, d1x, d1y, d2x, d2y, d3x, d3y);
}